// Round 5
// baseline (647.049 us; speedup 1.0000x reference)
//
#include <hip/hip_runtime.h>

// Round 5: two-level counting sort (dest_chunk, src_chunk) = 625 buckets.
//   R4 finding: bucket_scan 98% stalled (VALUBusy 1.76%) on random 16 B
//   charge gathers missing L2 (thrashed by the 128 MB entry stream) ->
//   L3-latency, MSHR-bound. Sorting entries by src chunk too makes the
//   gather window one 128 KiB chunk at a time: L1/L2-resident.
// Entry = (other_idx | local<<18 : u32, w : f32)  [natoms<2^18, local<2^13]
// ws: [counts 625 @0 | offsets 626 @4096 | cursors 625 @8192] (12 KiB hdr)
//     [entries 2*npairs*8 B][slabs C*NSLICES*128 KiB]

#define BLOCK 1024
#define NSLICES 10
#define UNROLL 8
#define CT_BLOCK 256
#define SC_BLOCK 512
#define SC_PPT 16         // pairs per thread in scatter (8192 pairs/block)
#define CA_BITS 13        // chunk = 8192 atoms
#define NCHUNK 25         // ceil(200000/8192)
#define NB (NCHUNK * NCHUNK)

// ---------------- Pass 0: count entries per (dest,src) bucket ----------------
__global__ __launch_bounds__(CT_BLOCK) void bucket_count(
    const int2* __restrict__ idx, unsigned* __restrict__ counts, int npairs)
{
    __shared__ unsigned hist[NB];
    for (int b = threadIdx.x; b < NB; b += CT_BLOCK) hist[b] = 0;
    __syncthreads();
    const int stride = gridDim.x * CT_BLOCK;
    for (int p = blockIdx.x * CT_BLOCK + threadIdx.x; p < npairs; p += stride) {
        int2 ij = idx[p];
        unsigned ci = (unsigned)ij.x >> CA_BITS;
        unsigned cj = (unsigned)ij.y >> CA_BITS;
        atomicAdd(&hist[ci * NCHUNK + cj], 1u);   // entry lands in dest ci, gathers from cj
        atomicAdd(&hist[cj * NCHUNK + ci], 1u);
    }
    __syncthreads();
    for (int b = threadIdx.x; b < NB; b += CT_BLOCK)
        if (hist[b]) atomicAdd(&counts[b], hist[b]);
}

// ---------------- prefix sum over 625 buckets ----------------
__global__ void bucket_prefix(const unsigned* __restrict__ counts,
                              unsigned* __restrict__ offsets,
                              unsigned* __restrict__ cursors)
{
    if (threadIdx.x == 0 && blockIdx.x == 0) {
        unsigned acc = 0;
        for (int b = 0; b < NB; ++b) {
            offsets[b] = acc; cursors[b] = acc; acc += counts[b];
        }
        offsets[NB] = acc;
    }
}

// ---------------- Pass A: scatter entries into bucket regions ----------------
__global__ __launch_bounds__(SC_BLOCK) void bucket_scatter(
    const int2*  __restrict__ idx, const float* __restrict__ dist,
    uint2* __restrict__ entries, unsigned* __restrict__ cursors, int npairs)
{
    __shared__ unsigned hist[NB];
    __shared__ unsigned base[NB];
    for (int b = threadIdx.x; b < NB; b += SC_BLOCK) hist[b] = 0;
    __syncthreads();

    const int p0 = blockIdx.x * (SC_BLOCK * SC_PPT) + threadIdx.x;
    unsigned key[2 * SC_PPT];
    unsigned brk[2 * SC_PPT];       // bucket(10b) | rank<<10 (rank < 16384)
    float    wv[SC_PPT];

#pragma unroll
    for (int k = 0; k < SC_PPT; ++k) {
        int p = p0 + k * SC_BLOCK;
        if (p < npairs) {
            int2 ij = idx[p];
            wv[k] = 0.5f / dist[p];
            unsigned ci = (unsigned)ij.x >> CA_BITS;
            unsigned cj = (unsigned)ij.y >> CA_BITS;
            unsigned b0 = ci * NCHUNK + cj;
            unsigned b1 = cj * NCHUNK + ci;
            key[2 * k]     = (unsigned)ij.y | (((unsigned)ij.x & ((1u << CA_BITS) - 1)) << 18);
            brk[2 * k]     = b0 | (atomicAdd(&hist[b0], 1u) << 10);
            key[2 * k + 1] = (unsigned)ij.x | (((unsigned)ij.y & ((1u << CA_BITS) - 1)) << 18);
            brk[2 * k + 1] = b1 | (atomicAdd(&hist[b1], 1u) << 10);
        } else {
            brk[2 * k] = brk[2 * k + 1] = 0xFFFFFFFFu;
        }
    }
    __syncthreads();
    for (int b = threadIdx.x; b < NB; b += SC_BLOCK)
        base[b] = hist[b] ? atomicAdd(&cursors[b], hist[b]) : 0u;
    __syncthreads();

#pragma unroll
    for (int k = 0; k < SC_PPT; ++k) {
        unsigned wbits = __float_as_uint(wv[k]);
        if (brk[2 * k] != 0xFFFFFFFFu) {
            unsigned b0 = brk[2 * k] & 1023u,     r0 = brk[2 * k] >> 10;
            unsigned b1 = brk[2 * k + 1] & 1023u, r1 = brk[2 * k + 1] >> 10;
            entries[base[b0] + r0] = make_uint2(key[2 * k],     wbits);
            entries[base[b1] + r1] = make_uint2(key[2 * k + 1], wbits);
        }
    }
}

// ---------------- Pass B: per-chunk LDS accumulate, src-ordered gathers ------
template<int CHUNK_ATOMS>
__global__ __launch_bounds__(BLOCK) void bucket_scan(
    const float4* __restrict__ charges, const uint2* __restrict__ entries,
    const unsigned* __restrict__ offsets, float* __restrict__ slabs,
    int natoms)
{
    constexpr int CH_ELEMS = CHUNK_ATOMS * 4;
    extern __shared__ float sm[];

    const int c  = blockIdx.x / NSLICES;
    const int s  = blockIdx.x - c * NSLICES;
    for (int e = threadIdx.x; e < CH_ELEMS; e += BLOCK) sm[e] = 0.f;
    __syncthreads();

    const unsigned beg = offsets[c * NCHUNK];           // region = all src buckets of dest c
    const unsigned cnt = offsets[(c + 1) * NCHUNK] - beg;
    const unsigned e0  = beg + (unsigned)((unsigned long long)cnt * s       / NSLICES);
    const unsigned e1  = beg + (unsigned)((unsigned long long)cnt * (s + 1) / NSLICES);

    unsigned e = e0 + threadIdx.x;
    const unsigned nb = (e1 > e0) ? (e1 - e0) / (BLOCK * 4) : 0;
    for (unsigned b = 0; b < nb; ++b, e += BLOCK * 4) {
        uint2 en[4];
#pragma unroll
        for (int u = 0; u < 4; ++u) en[u] = entries[e + u * BLOCK];
        float4 cq[4];
#pragma unroll
        for (int u = 0; u < 4; ++u) cq[u] = charges[en[u].x & 0x3FFFFu];
#pragma unroll
        for (int u = 0; u < 4; ++u) {
            float w = __uint_as_float(en[u].y);
            float* bp = sm + (en[u].x >> 18) * 4;
            atomicAdd(bp + 0, cq[u].x * w);
            atomicAdd(bp + 1, cq[u].y * w);
            atomicAdd(bp + 2, cq[u].z * w);
            atomicAdd(bp + 3, cq[u].w * w);
        }
    }
    for (; e < e1; e += BLOCK) {
        uint2 en = entries[e];
        float4 cq = charges[en.x & 0x3FFFFu];
        float w = __uint_as_float(en.y);
        float* bp = sm + (en.x >> 18) * 4;
        atomicAdd(bp + 0, cq.x * w);
        atomicAdd(bp + 1, cq.y * w);
        atomicAdd(bp + 2, cq.z * w);
        atomicAdd(bp + 3, cq.w * w);
    }
    __syncthreads();

    const int c0 = c * CHUNK_ATOMS;
    const int nvalid = min(CHUNK_ATOMS, natoms - c0) * 4;
    float* dst = slabs + (size_t)blockIdx.x * CH_ELEMS;
    for (int e2 = threadIdx.x; e2 < nvalid; e2 += BLOCK) dst[e2] = sm[e2];
}

// ---------------- slab reduce ----------------
template<int CH_ELEMS>
__global__ __launch_bounds__(256) void chunk_reduce(
    const float* __restrict__ ws, float* __restrict__ out, int total)
{
    int g = blockIdx.x * blockDim.x + threadIdx.x;
    if (g >= total) return;
    int c     = g / CH_ELEMS;
    int local = g - c * CH_ELEMS;
    const float* p = ws + ((size_t)c * NSLICES) * CH_ELEMS + local;
    float acc = 0.f;
#pragma unroll
    for (int s = 0; s < NSLICES; ++s) acc += p[(size_t)s * CH_ELEMS];
    out[g] = acc;
}

// ---------------- Fallback: R3 redundant chunk scan ----------------
template<int CHUNK_ATOMS, bool USE_WS>
__global__ __launch_bounds__(BLOCK) void chunk_scan(
    const float4* __restrict__ charges, const int2* __restrict__ idx,
    const float* __restrict__ dist, float* __restrict__ dest,
    int npairs, int natoms)
{
    constexpr int CH_ELEMS = CHUNK_ATOMS * 4;
    extern __shared__ float sm[];
    const int c  = blockIdx.x / NSLICES;
    const int s  = blockIdx.x - c * NSLICES;
    const int c0 = c * CHUNK_ATOMS;
    const int cn = min(CHUNK_ATOMS, natoms - c0);
    for (int e = threadIdx.x; e < CH_ELEMS; e += BLOCK) sm[e] = 0.f;
    __syncthreads();
    const int p0 = (int)((long long)npairs * s       / NSLICES);
    const int p1 = (int)((long long)npairs * (s + 1) / NSLICES);
    const int nbatch = (p1 - p0) / (BLOCK * UNROLL);
    int p = p0 + threadIdx.x;
    for (int b = 0; b < nbatch; ++b, p += BLOCK * UNROLL) {
        int2 ij[UNROLL]; float dd[UNROLL];
#pragma unroll
        for (int u = 0; u < UNROLL; ++u) { ij[u] = idx[p + u * BLOCK]; dd[u] = dist[p + u * BLOCK]; }
#pragma unroll
        for (int u = 0; u < UNROLL; ++u) {
            unsigned li = (unsigned)(ij[u].x - c0), lj = (unsigned)(ij[u].y - c0);
            float w = 0.5f / dd[u];
            if (li < (unsigned)cn) {
                float4 cq = charges[ij[u].y]; float* bp = sm + li * 4;
                atomicAdd(bp + 0, cq.x * w); atomicAdd(bp + 1, cq.y * w);
                atomicAdd(bp + 2, cq.z * w); atomicAdd(bp + 3, cq.w * w);
            }
            if (lj < (unsigned)cn) {
                float4 cq = charges[ij[u].x]; float* bp = sm + lj * 4;
                atomicAdd(bp + 0, cq.x * w); atomicAdd(bp + 1, cq.y * w);
                atomicAdd(bp + 2, cq.z * w); atomicAdd(bp + 3, cq.w * w);
            }
        }
    }
    for (; p < p1; p += BLOCK) {
        int2 ij = idx[p];
        unsigned li = (unsigned)(ij.x - c0), lj = (unsigned)(ij.y - c0);
        if (li < (unsigned)cn || lj < (unsigned)cn) {
            float w = 0.5f / dist[p];
            if (li < (unsigned)cn) {
                float4 cq = charges[ij.y]; float* bp = sm + li * 4;
                atomicAdd(bp + 0, cq.x * w); atomicAdd(bp + 1, cq.y * w);
                atomicAdd(bp + 2, cq.z * w); atomicAdd(bp + 3, cq.w * w);
            }
            if (lj < (unsigned)cn) {
                float4 cq = charges[ij.x]; float* bp = sm + lj * 4;
                atomicAdd(bp + 0, cq.x * w); atomicAdd(bp + 1, cq.y * w);
                atomicAdd(bp + 2, cq.z * w); atomicAdd(bp + 3, cq.w * w);
            }
        }
    }
    __syncthreads();
    const int nvalid = cn * 4;
    if (USE_WS) {
        float* dst = dest + (size_t)blockIdx.x * CH_ELEMS;
        for (int e = threadIdx.x; e < nvalid; e += BLOCK) dst[e] = sm[e];
    } else {
        float* dst = dest + (size_t)c0 * 4;
        for (int e = threadIdx.x; e < nvalid; e += BLOCK) atomicAdd(dst + e, sm[e]);
    }
}

extern "C" void kernel_launch(void* const* d_in, const int* in_sizes, int n_in,
                              void* d_out, int out_size, void* d_ws, size_t ws_size,
                              hipStream_t stream) {
    const float4* charges = (const float4*)d_in[0];
    const int2*   idx     = (const int2*)  d_in[1];
    const float*  dist    = (const float*) d_in[2];
    float*        out     = (float*)d_out;

    const int natoms = in_sizes[0] / 4;     // 200000
    const int npairs = in_sizes[2];         // 8000000
    const int total  = out_size;            // 800000

    int dev = 0;
    hipGetDevice(&dev);
    int maxShm = 0;
    hipDeviceGetAttribute(&maxShm, hipDeviceAttributeMaxSharedMemoryPerBlock, dev);
    const bool big = (maxShm >= 131072);

    constexpr int CA = 8192, CE = CA * 4;
    const int C    = (natoms + CA - 1) / CA;       // 25
    const int grid = C * NSLICES;                  // 250

    const size_t HDR        = 12288;
    const size_t ent_bytes  = (size_t)2 * npairs * sizeof(uint2);  // 128 MB
    size_t slab_off         = (HDR + ent_bytes + 255) & ~(size_t)255;
    const size_t slab_bytes = (size_t)grid * CE * sizeof(float);   // 32.8 MB
    const size_t need       = slab_off + slab_bytes;

    if (big && ws_size >= need && natoms <= (1 << 18) && C == NCHUNK) {
        unsigned* counts  = (unsigned*)d_ws;                 // [625]
        unsigned* offsets = (unsigned*)((char*)d_ws + 4096); // [626]
        unsigned* cursors = (unsigned*)((char*)d_ws + 8192); // [625]
        uint2*    entries = (uint2*)((char*)d_ws + HDR);
        float*    slabs   = (float*)((char*)d_ws + slab_off);

        hipMemsetAsync(d_ws, 0, HDR, stream);
        bucket_count<<<2048, CT_BLOCK, 0, stream>>>(idx, counts, npairs);
        bucket_prefix<<<1, 32, 0, stream>>>(counts, offsets, cursors);
        const int sc_grid = (npairs + SC_BLOCK * SC_PPT - 1) / (SC_BLOCK * SC_PPT);
        bucket_scatter<<<sc_grid, SC_BLOCK, 0, stream>>>(idx, dist, entries, cursors, npairs);
        hipFuncSetAttribute((const void*)bucket_scan<CA>,
                            hipFuncAttributeMaxDynamicSharedMemorySize, CE * 4);
        bucket_scan<CA><<<grid, BLOCK, CE * 4, stream>>>(charges, entries, offsets, slabs, natoms);
        chunk_reduce<CE><<<(total + 255) / 256, 256, 0, stream>>>(slabs, out, total);
    } else if (big) {
        const size_t ws_need = (size_t)grid * CE * sizeof(float);
        if (ws_size >= ws_need) {
            hipFuncSetAttribute((const void*)chunk_scan<CA, true>,
                                hipFuncAttributeMaxDynamicSharedMemorySize, CE * 4);
            chunk_scan<CA, true><<<grid, BLOCK, CE * 4, stream>>>(
                charges, idx, dist, (float*)d_ws, npairs, natoms);
            chunk_reduce<CE><<<(total + 255) / 256, 256, 0, stream>>>(
                (const float*)d_ws, out, total);
        } else {
            hipMemsetAsync(d_out, 0, (size_t)total * sizeof(float), stream);
            hipFuncSetAttribute((const void*)chunk_scan<CA, false>,
                                hipFuncAttributeMaxDynamicSharedMemorySize, CE * 4);
            chunk_scan<CA, false><<<grid, BLOCK, CE * 4, stream>>>(
                charges, idx, dist, out, npairs, natoms);
        }
    } else {
        constexpr int CA2 = 4096, CE2 = CA2 * 4;
        const int C2 = (natoms + CA2 - 1) / CA2;
        const int grid2 = C2 * NSLICES;
        const size_t ws_need = (size_t)grid2 * CE2 * sizeof(float);
        if (ws_size >= ws_need) {
            chunk_scan<CA2, true><<<grid2, BLOCK, CE2 * 4, stream>>>(
                charges, idx, dist, (float*)d_ws, npairs, natoms);
            chunk_reduce<CE2><<<(total + 255) / 256, 256, 0, stream>>>(
                (const float*)d_ws, out, total);
        } else {
            hipMemsetAsync(d_out, 0, (size_t)total * sizeof(float), stream);
            chunk_scan<CA2, false><<<grid2, BLOCK, CE2 * 4, stream>>>(
                charges, idx, dist, out, npairs, natoms);
        }
    }
}